// Round 2
// baseline (239.119 us; speedup 1.0000x reference)
//
#include <hip/hip_runtime.h>
#include <hip/hip_cooperative_groups.h>

namespace cg = cooperative_groups;

// out[b,h] = xbar[b,h] + sum_j xbar[b,j]*Wv[h,j] + bv[h],  xbar = x.mean(axis=0)
// (softmax over the query axis makes attention collapse to mean_k V — exact math,
//  verified round 1 with absmax 0.0)

constexpr int S = 1024, B = 16, H = 1024;
constexpr int C  = B * H;      // 16384 columns of x viewed [S][B*H]
constexpr int C4 = C / 4;      // 4096 float4 columns
constexpr int SPLITS = 64;     // S-splits for phase 1
constexpr int ROWS = S / SPLITS;  // 16 rows per block
constexpr int NB = 1024;       // grid  (4 blocks/CU on 256 CUs)
constexpr int NT = 256;        // block (4 waves)

// ---- phase 1: partial column sums. block bx: column-chunk (bx&15), split (bx>>4).
__device__ __forceinline__ void phase1(const float4* __restrict__ x4,
                                       float* __restrict__ part, int bx, int tid) {
    const int cx = bx & 15, y = bx >> 4;            // 16 chunks x 64 splits
    const int c4 = cx * NT + tid;                   // [0, 4096)
    const float4* p = x4 + (size_t)y * ROWS * C4 + c4;
    float4 a = make_float4(0.f, 0.f, 0.f, 0.f);
#pragma unroll 4
    for (int i = 0; i < ROWS; ++i) {
        float4 v = p[(size_t)i * C4];
        a.x += v.x; a.y += v.y; a.z += v.z; a.w += v.w;
    }
    reinterpret_cast<float4*>(part)[(size_t)y * C4 + c4] = a;
}

// ---- phase 2: fold 64 partial rows -> xsum[C]. 16 threads/column, shfl combine.
__device__ __forceinline__ void phase2(const float* __restrict__ part,
                                       float* __restrict__ xsum, int bx, int tid) {
    const int g   = bx * NT + tid;
    const int l   = tid & 63;
    const int wid = g >> 6;          // [0, 4096) waves
    const int cb  = wid * 4;         // 4 columns per wave
    const int k   = l >> 2;          // [0,16): which group of 4 partials
    const int c   = cb + (l & 3);
    float a = 0.f;
#pragma unroll
    for (int i = 0; i < 4; ++i) a += part[(size_t)(k * 4 + i) * C + c];
    a += __shfl_xor(a, 4, 64);
    a += __shfl_xor(a, 8, 64);
    a += __shfl_xor(a, 16, 64);
    a += __shfl_xor(a, 32, 64);
    if (l < 4) xsum[c] = a;
}

// ---- phase 3: out[b,h]. block bx: b-group (bx>>8), h = (bx&255)*4 + wave.
__device__ __forceinline__ void phase3(const float* __restrict__ xsum,
                                       const float* __restrict__ Wv,
                                       const float* __restrict__ bv,
                                       float* __restrict__ out,
                                       float* __restrict__ xs,   // LDS, 4*H floats
                                       int bx, int tid) {
    const int bgrp = bx >> 8;   // [0,4): rows bgrp*4 .. bgrp*4+3
    {
        const float4* src = reinterpret_cast<const float4*>(xsum + bgrp * 4 * H);
        float4* dst = reinterpret_cast<float4*>(xs);
#pragma unroll
        for (int j = 0; j < 4; ++j) dst[tid + j * NT] = src[tid + j * NT];
    }
    __syncthreads();
    const int w = tid >> 6, l = tid & 63;
    const int h = (bx & 255) * 4 + w;
    const float4* wr = reinterpret_cast<const float4*>(Wv + (size_t)h * H);
    const float4 w0 = wr[l], w1 = wr[l + 64], w2 = wr[l + 128], w3 = wr[l + 192];
#pragma unroll
    for (int i = 0; i < 4; ++i) {
        const float4* xr = reinterpret_cast<const float4*>(xs + i * H);
        const float4 a0 = xr[l], a1 = xr[l + 64], a2 = xr[l + 128], a3 = xr[l + 192];
        float acc = a0.x * w0.x + a0.y * w0.y + a0.z * w0.z + a0.w * w0.w
                  + a1.x * w1.x + a1.y * w1.y + a1.z * w1.z + a1.w * w1.w
                  + a2.x * w2.x + a2.y * w2.y + a2.z * w2.z + a2.w * w2.w
                  + a3.x * w3.x + a3.y * w3.y + a3.z * w3.z + a3.w * w3.w;
#pragma unroll
        for (int off = 32; off; off >>= 1) acc += __shfl_down(acc, off, 64);
        if (l == 0) {
            const int b = bgrp * 4 + i;
            out[b * H + h] = (xs[i * H + h] + acc) * (1.0f / (float)S) + bv[h];
        }
    }
}

// ---- fused cooperative kernel
__global__ void __launch_bounds__(NT, 4) k_fused(const float4* __restrict__ x4,
                                                 const float* __restrict__ Wv,
                                                 const float* __restrict__ bv,
                                                 float* __restrict__ out,
                                                 float* __restrict__ ws) {
    __shared__ float xs[4 * H];   // 16 KB
    cg::grid_group grid = cg::this_grid();
    float* part = ws;                         // [SPLITS][C]  (4 MB)
    float* xsum = ws + (size_t)SPLITS * C;    // [C]
    phase1(x4, part, blockIdx.x, threadIdx.x);
    grid.sync();
    phase2(part, xsum, blockIdx.x, threadIdx.x);
    grid.sync();
    phase3(xsum, Wv, bv, out, xs, blockIdx.x, threadIdx.x);
}

// ---- fallback: same phases as ordinary kernels
__global__ void __launch_bounds__(NT) k_p1(const float4* __restrict__ x4,
                                           float* __restrict__ part) {
    phase1(x4, part, blockIdx.x, threadIdx.x);
}
__global__ void __launch_bounds__(NT) k_p2(const float* __restrict__ part,
                                           float* __restrict__ xsum) {
    phase2(part, xsum, blockIdx.x, threadIdx.x);
}
__global__ void __launch_bounds__(NT) k_p3(const float* __restrict__ xsum,
                                           const float* __restrict__ Wv,
                                           const float* __restrict__ bv,
                                           float* __restrict__ out) {
    __shared__ float xs[4 * H];
    phase3(xsum, Wv, bv, out, xs, blockIdx.x, threadIdx.x);
}

extern "C" void kernel_launch(void* const* d_in, const int* in_sizes, int n_in,
                              void* d_out, int out_size, void* d_ws, size_t ws_size,
                              hipStream_t stream) {
    const float4* x4 = (const float4*)d_in[0];
    // d_in[1..4] (Wq,bq,Wk,bk) are provably unused — softmax over the query
    // axis sums to 1 along q, so Q and K cancel out of the output exactly.
    const float* Wv = (const float*)d_in[5];
    const float* bv = (const float*)d_in[6];
    float* out = (float*)d_out;
    float* ws  = (float*)d_ws;
    float* part = ws;
    float* xsum = ws + (size_t)SPLITS * C;

    void* args[] = { (void*)&x4, (void*)&Wv, (void*)&bv, (void*)&out, (void*)&ws };
    hipError_t e = hipLaunchCooperativeKernel((const void*)k_fused,
                                              dim3(NB), dim3(NT), args, 0, stream);
    if (e != hipSuccess) {
        (void)hipGetLastError();   // clear, take the 3-kernel path
        k_p1<<<NB, NT, 0, stream>>>(x4, part);
        k_p2<<<NB, NT, 0, stream>>>(part, xsum);
        k_p3<<<NB, NT, 0, stream>>>(xsum, Wv, bv, out);
    }
}

// Round 3
// 39.512 us; speedup vs baseline: 6.0518x; 6.0518x over previous
//
#include <hip/hip_runtime.h>

// Algebraic collapse (verified exactly in rounds 1-2, absmax <= 1.5e-5):
//   softmax over the QUERY axis => sum_q attn[b,q,k] == 1 for all (b,k), so
//   context.mean(axis=0) = mean_k V[k,b,:] = xbar @ Wv.T + bv, and
//   out[b,h] = xbar[b,h] + sum_j xbar[b,j]*Wv[h,j] + bv[h],  xbar = x.mean(0).
//   Wq, bq, Wk, bk drop out of the output entirely.
// Round-2 lesson: NO cooperative grid.sync on MI355X (~100us/sync across
// 8 XCDs). Plain kernel boundaries cost ~1-2us each instead.

constexpr int S = 1024, B = 16, H = 1024;
constexpr int C  = B * H;        // 16384 columns of x viewed [S][B*H]
constexpr int C4 = C / 4;        // 4096 float4 columns
constexpr int SPLITS = 64;       // S-splits for K1
constexpr int ROWS = S / SPLITS; // 16 rows per block

// ---- K1: partial column sums. grid (16, 64) = 1024 blocks (4/CU), block 256.
// Each thread: 16 float4 loads (fully unrolled -> 16 in flight), 1 float4 store.
__global__ void __launch_bounds__(256) k_colsum(const float4* __restrict__ x4,
                                                float4* __restrict__ part4) {
    const int c4 = blockIdx.x * 256 + threadIdx.x;  // [0, 4096)
    const int y  = blockIdx.y;                      // [0, 64)
    const float4* p = x4 + (size_t)y * ROWS * C4 + c4;
    float4 a = make_float4(0.f, 0.f, 0.f, 0.f);
#pragma unroll
    for (int i = 0; i < ROWS; ++i) {
        float4 v = p[(size_t)i * C4];
        a.x += v.x; a.y += v.y; a.z += v.z; a.w += v.w;
    }
    part4[(size_t)y * C4 + c4] = a;
}

// ---- K2: fold 64 partial rows -> xsum[C]. 64 blocks, fully coalesced.
__global__ void __launch_bounds__(256) k_fold(const float* __restrict__ part,
                                              float* __restrict__ xsum) {
    const int c = blockIdx.x * 256 + threadIdx.x;   // [0, 16384)
    float a = 0.f;
#pragma unroll
    for (int t = 0; t < SPLITS; ++t) a += part[(size_t)t * C + c];
    xsum[c] = a;
}

// ---- K3: out[b,h] = (xsum[b,h] + dot(xsum[b,:], Wv[h,:])) / S + bv[h].
// 256 blocks x 256 threads. Whole xsum staged in LDS (64 KB) once per block;
// wave w owns h = bx*4 + w for ALL 16 b => each Wv row fetched exactly once.
__global__ void __launch_bounds__(256) k_out(const float* __restrict__ xsum,
                                             const float* __restrict__ Wv,
                                             const float* __restrict__ bv,
                                             float* __restrict__ out) {
    __shared__ float xs[C];   // 64 KB
    {
        const float4* src = reinterpret_cast<const float4*>(xsum);
        float4* dst = reinterpret_cast<float4*>(xs);
#pragma unroll
        for (int j = 0; j < C4 / 256; ++j)          // 16 float4 per thread
            dst[threadIdx.x + j * 256] = src[threadIdx.x + j * 256];
    }
    __syncthreads();

    const int w = threadIdx.x >> 6, l = threadIdx.x & 63;
    const int h = blockIdx.x * 4 + w;               // [0, 1024)
    const float4* wr = reinterpret_cast<const float4*>(Wv + (size_t)h * H);
    const float4 w0 = wr[l], w1 = wr[l + 64], w2 = wr[l + 128], w3 = wr[l + 192];
    const float bvh = bv[h];

#pragma unroll
    for (int b = 0; b < B; ++b) {
        const float4* xr = reinterpret_cast<const float4*>(xs + b * H);
        const float4 a0 = xr[l], a1 = xr[l + 64], a2 = xr[l + 128], a3 = xr[l + 192];
        float acc = a0.x * w0.x + a0.y * w0.y + a0.z * w0.z + a0.w * w0.w
                  + a1.x * w1.x + a1.y * w1.y + a1.z * w1.z + a1.w * w1.w
                  + a2.x * w2.x + a2.y * w2.y + a2.z * w2.z + a2.w * w2.w
                  + a3.x * w3.x + a3.y * w3.y + a3.z * w3.z + a3.w * w3.w;
#pragma unroll
        for (int off = 32; off; off >>= 1) acc += __shfl_down(acc, off, 64);
        if (l == 0)
            out[b * H + h] = (xs[b * H + h] + acc) * (1.0f / (float)S) + bvh;
    }
}

extern "C" void kernel_launch(void* const* d_in, const int* in_sizes, int n_in,
                              void* d_out, int out_size, void* d_ws, size_t ws_size,
                              hipStream_t stream) {
    const float4* x4 = (const float4*)d_in[0];
    // d_in[1..4] (Wq,bq,Wk,bk) provably unused — they cancel exactly (header).
    const float* Wv = (const float*)d_in[5];
    const float* bv = (const float*)d_in[6];
    float* out  = (float*)d_out;
    float* ws   = (float*)d_ws;
    float* part = ws;                        // [SPLITS][C]  = 4 MiB
    float* xsum = ws + (size_t)SPLITS * C;   // [C]          = 64 KiB

    k_colsum<<<dim3(16, SPLITS), 256, 0, stream>>>(x4, (float4*)part);
    k_fold<<<C / 256, 256, 0, stream>>>(part, xsum);
    k_out<<<256, 256, 0, stream>>>(xsum, Wv, bv, out);
}

// Round 4
// 38.447 us; speedup vs baseline: 6.2194x; 1.0277x over previous
//
#include <hip/hip_runtime.h>

// Algebraic collapse (verified exactly, absmax 0.0 in rounds 1/3):
//   softmax over the QUERY axis => sum_q attn[b,q,k] == 1 for all (b,k), so
//   context.mean(axis=0) = mean_k V[k,b,:] = xbar @ Wv.T + bv, and
//   out[b,h] = xbar[b,h] + sum_j xbar[b,j]*Wv[h,j] + bv[h],  xbar = x.mean(0).
//   Wq, bq, Wk, bk drop out of the output entirely.
// Lessons so far:
//   R2: NO cooperative grid.sync on MI355X (~100us/sync). Plain boundaries.
//   R3: 39.5us vs R1 25.1us. Changed: (a) colsum 512->1024 blocks,
//       (b) k_out -> 256 blocks w/ 64KB LDS (1 wave/SIMD, bank-conflicted,
//       dependent shfl chains exposed). This round keeps (a), reverts (b)
//       to R1's proven 4096-block wave-per-(b,h) design => clean bisect.

constexpr int S = 1024, B = 16, H = 1024;
constexpr int C  = B * H;        // 16384 columns of x viewed [S][B*H]
constexpr int C4 = C / 4;        // 4096 float4 columns
constexpr int SPLITS = 64;       // S-splits for K1
constexpr int ROWS = S / SPLITS; // 16 rows per block

// ---- K1: partial column sums. grid (16, 64) = 1024 blocks (4/CU), block 256.
__global__ void __launch_bounds__(256) k_colsum(const float4* __restrict__ x4,
                                                float4* __restrict__ part4) {
    const int c4 = blockIdx.x * 256 + threadIdx.x;  // [0, 4096)
    const int y  = blockIdx.y;                      // [0, 64)
    const float4* p = x4 + (size_t)y * ROWS * C4 + c4;
    float4 a = make_float4(0.f, 0.f, 0.f, 0.f);
#pragma unroll
    for (int i = 0; i < ROWS; ++i) {
        float4 v = p[(size_t)i * C4];
        a.x += v.x; a.y += v.y; a.z += v.z; a.w += v.w;
    }
    part4[(size_t)y * C4 + c4] = a;
}

// ---- K2: fold 64 partial rows -> xsum[C]. 64 blocks, fully coalesced.
__global__ void __launch_bounds__(256) k_fold(const float* __restrict__ part,
                                              float* __restrict__ xsum) {
    const int c = blockIdx.x * 256 + threadIdx.x;   // [0, 16384)
    float a = 0.f;
#pragma unroll
    for (int t = 0; t < SPLITS; ++t) a += part[(size_t)t * C + c];
    xsum[c] = a;
}

// ---- K3 (R1-proven): one wave per output element, no LDS.
// grid 4096 blocks x 256 thr = 16384 waves; wave -> (b,h).
__global__ void __launch_bounds__(256) k_out(const float* __restrict__ xsum,
                                             const float* __restrict__ Wv,
                                             const float* __restrict__ bv,
                                             float* __restrict__ out) {
    const int wid = (blockIdx.x * 256 + threadIdx.x) >> 6;  // [0, 16384)
    const int lane = threadIdx.x & 63;
    const int b = wid >> 10;      // [0,16)
    const int h = wid & 1023;     // [0,1024)
    const float4* xr = (const float4*)(xsum + (size_t)b * H);
    const float4* wr = (const float4*)(Wv + (size_t)h * H);
    float acc = 0.f;
#pragma unroll
    for (int it = 0; it < 4; ++it) {
        const int j4 = lane + it * 64;          // 256 float4 per row
        float4 xv = xr[j4];
        float4 wv = wr[j4];
        acc += xv.x * wv.x + xv.y * wv.y + xv.z * wv.z + xv.w * wv.w;
    }
#pragma unroll
    for (int off = 32; off; off >>= 1) acc += __shfl_down(acc, off, 64);
    if (lane == 0) {
        const int c = b * H + h;
        out[c] = (xsum[c] + acc) * (1.0f / (float)S) + bv[h];
    }
}

extern "C" void kernel_launch(void* const* d_in, const int* in_sizes, int n_in,
                              void* d_out, int out_size, void* d_ws, size_t ws_size,
                              hipStream_t stream) {
    const float4* x4 = (const float4*)d_in[0];
    // d_in[1..4] (Wq,bq,Wk,bk) provably unused — they cancel exactly (header).
    const float* Wv = (const float*)d_in[5];
    const float* bv = (const float*)d_in[6];
    float* out  = (float*)d_out;
    float* ws   = (float*)d_ws;
    float* part = ws;                        // [SPLITS][C]  = 4 MiB
    float* xsum = ws + (size_t)SPLITS * C;   // [C]          = 64 KiB

    k_colsum<<<dim3(16, SPLITS), 256, 0, stream>>>(x4, (float4*)part);
    k_fold<<<C / 256, 256, 0, stream>>>(part, xsum);
    k_out<<<16384 / 4, 256, 0, stream>>>(xsum, Wv, bv, out);
}

// Round 5
// 25.207 us; speedup vs baseline: 9.4861x; 1.5252x over previous
//
#include <hip/hip_runtime.h>

// Algebraic collapse (verified exactly, absmax 0.0 across rounds):
//   softmax over the QUERY axis => sum_q attn[b,q,k] == 1 for all (b,k), so
//   context.mean(axis=0) = mean_k V[k,b,:] = xbar @ Wv.T + bv, and
//   out[b,h] = xbar[b,h] + sum_j xbar[b,j]*Wv[h,j] + bv[h],  xbar = x.mean(0).
//   Wq, bq, Wk, bk drop out of the output entirely.
// Lessons:
//   R2: NO cooperative grid.sync on MI355X (~100us/sync). Plain boundaries.
//   R3/R4 bisect: k_out reverted -> still ~38us. Only remaining delta vs
//   R1 (25.1us) is SPLITS 32->64 in colsum/fold. This round: EXACT R1
//   reproduce (A/A test). ~25 => SPLITS matters (investigate why);
//   ~38 => R1 was an outlier, noise band is +/-13us.

constexpr int S = 1024;
constexpr int B = 16;
constexpr int H = 1024;
constexpr int C = B * H;            // 16384 columns when x is viewed [S][B*H]
constexpr int SPLITS = 32;          // S-axis split for kernel 1
constexpr int SCHUNK = S / SPLITS;  // 32 rows per block

// --- K1: partial column sums, float4 across columns.
// grid (C/4/256, SPLITS) = (16, 32), block 256.
__global__ void k_colsum(const float4* __restrict__ x4, float4* __restrict__ part4) {
    const int c4 = blockIdx.x * blockDim.x + threadIdx.x;   // [0, C/4)
    const int split = blockIdx.y;
    const float4* p = x4 + (size_t)split * SCHUNK * (C / 4) + c4;
    float4 a = make_float4(0.f, 0.f, 0.f, 0.f);
#pragma unroll
    for (int i = 0; i < SCHUNK; ++i) {
        float4 v = p[(size_t)i * (C / 4)];
        a.x += v.x; a.y += v.y; a.z += v.z; a.w += v.w;
    }
    part4[(size_t)split * (C / 4) + c4] = a;
}

// --- K1.5: fold SPLITS partial rows -> xsum[C] (raw sums over S, unscaled).
// grid C/256 = 64, block 256.
__global__ void k_reduce(const float* __restrict__ part, float* __restrict__ xsum) {
    const int c = blockIdx.x * blockDim.x + threadIdx.x;
    float a = 0.f;
#pragma unroll
    for (int t = 0; t < SPLITS; ++t) a += part[(size_t)t * C + c];
    xsum[c] = a;
}

// --- K2: one wave per output element.
// out[b*H+h] = (xsum[b*H+h] + sum_j xsum[b*H+j]*Wv[h*H+j]) / S + bv[h]
// grid 4096, block 256 (4 waves/block) -> 16384 waves.
__global__ void k_out(const float* __restrict__ xsum, const float* __restrict__ Wv,
                      const float* __restrict__ bv, float* __restrict__ out) {
    const int wid = (blockIdx.x * blockDim.x + threadIdx.x) >> 6;  // [0, 16384)
    const int lane = threadIdx.x & 63;
    const int b = wid >> 10;      // [0,16)
    const int h = wid & 1023;     // [0,1024)
    const float4* xr = (const float4*)(xsum + (size_t)b * H);
    const float4* wr = (const float4*)(Wv + (size_t)h * H);
    float acc = 0.f;
#pragma unroll
    for (int it = 0; it < 4; ++it) {
        const int j4 = lane + it * 64;          // 256 float4 per row
        float4 xv = xr[j4];
        float4 wv = wr[j4];
        acc += xv.x * wv.x + xv.y * wv.y + xv.z * wv.z + xv.w * wv.w;
    }
#pragma unroll
    for (int off = 32; off > 0; off >>= 1) acc += __shfl_down(acc, off, 64);
    if (lane == 0) {
        const int c = b * H + h;
        out[c] = (xsum[c] + acc) * (1.0f / (float)S) + bv[h];
    }
}

extern "C" void kernel_launch(void* const* d_in, const int* in_sizes, int n_in,
                              void* d_out, int out_size, void* d_ws, size_t ws_size,
                              hipStream_t stream) {
    const float* x  = (const float*)d_in[0];
    // d_in[1..4] (Wq,bq,Wk,bk) are provably unused (see header).
    const float* Wv = (const float*)d_in[5];
    const float* bv = (const float*)d_in[6];
    float* out = (float*)d_out;
    float* ws  = (float*)d_ws;

    float* part = ws;                       // [SPLITS][C]  = 2 MiB
    float* xsum = ws + (size_t)SPLITS * C;  // [C]
    k_colsum<<<dim3(C / 4 / 256, SPLITS), 256, 0, stream>>>(
        (const float4*)x, (float4*)part);
    k_reduce<<<C / 256, 256, 0, stream>>>(part, xsum);
    k_out<<<16384 / 4, 256, 0, stream>>>(xsum, Wv, bv, out);
}